// Round 9
// baseline (1140.286 us; speedup 1.0000x reference)
//
#include <hip/hip_runtime.h>
#include <float.h>
#include <math.h>

#define NB 2
#define NPROP 512
#define NROI 1024        // NB*NPROP
#define CFEAT 256
#define FH 200
#define FW 200
#define HWSZ 40000
#define INDIM 12544      // 256*49
#define FCD 1024
#define NCLS 81
#define NCAND 40960      // per batch: 512*80
#define CAP 4096
#define NSEL 2048
#define DETS 100
#define CLIPV 4.135166556742356f

#define KKT1 392         // 12544/32
#define KKT2 32          // 1024/32
#define SPLITK 8

typedef __attribute__((ext_vector_type(8))) short short8v;
typedef __attribute__((ext_vector_type(8))) unsigned short ushort8v;
typedef __attribute__((ext_vector_type(4))) float float4v;

// ---------------- helpers: bf16 triple split ----------------
__device__ __forceinline__ unsigned short f2bf(float x) {
    unsigned u = __float_as_uint(x);
    unsigned r = (u + 0x7fffu + ((u >> 16) & 1u)) >> 16;
    return (unsigned short)r;
}
__device__ __forceinline__ float bf2f(unsigned short b) {
    return __uint_as_float(((unsigned)b) << 16);
}
__device__ __forceinline__ void split3(float x, unsigned short& h, unsigned short& m, unsigned short& l) {
    h = f2bf(x);
    float r1 = x - bf2f(h);
    m = f2bf(r1);
    float r2 = r1 - bf2f(m);
    l = f2bf(r2);
}

__device__ __forceinline__ void gload_lds16(const void* g, void* l) {
    __builtin_amdgcn_global_load_lds((const __attribute__((address_space(1))) unsigned int*)g,
                                     (__attribute__((address_space(3))) unsigned int*)l, 16, 0, 0);
}

// swizzle involution on byte offsets within an 8KB tile
__device__ __forceinline__ int swz8k(int o) {
    return o ^ ((((o >> 6) ^ (o >> 8)) & 3) << 4);
}

// ---------------- zero counters ----------------
__global__ void zero_ints_k(int* p, int n) {
    int i = blockIdx.x * blockDim.x + threadIdx.x;
    if (i < n) p[i] = 0;
}

// ---------------- feature transpose NCHW -> NHWC ----------------
__global__ __launch_bounds__(256) void transpose_k(const float* __restrict__ in, float* __restrict__ out) {
    __shared__ float tile[32][33];
    int b = blockIdx.z;
    int hw0 = blockIdx.x * 32;
    int c0 = blockIdx.y * 32;
    int tx = threadIdx.x;
    int ty = threadIdx.y;
#pragma unroll
    for (int i = 0; i < 32; i += 8)
        tile[ty + i][tx] = in[((size_t)(b * CFEAT + c0 + ty + i)) * HWSZ + hw0 + tx];
    __syncthreads();
#pragma unroll
    for (int i = 0; i < 32; i += 8)
        out[((size_t)b * HWSZ + hw0 + ty + i) * CFEAT + c0 + tx] = tile[tx][ty + i];
}

// ---------------- bilinear core (scalar, fallback) ----------------
template<bool TRANS>
__device__ __forceinline__ float bil_sample(const float* __restrict__ feat, int b, int c,
                                            float yy, float xx) {
    bool valid = (yy > -1.f) && (yy < (float)FH) && (xx > -1.f) && (xx < (float)FW);
    float yc = fminf(fmaxf(yy, 0.f), (float)(FH - 1));
    float xc = fminf(fmaxf(xx, 0.f), (float)(FW - 1));
    int y0 = (int)floorf(yc), x0 = (int)floorf(xc);
    int y1i = min(y0 + 1, FH - 1), x1i = min(x0 + 1, FW - 1);
    float ly = yc - (float)y0, lx = xc - (float)x0;
    float hy = 1.f - ly, hx = 1.f - lx;
    float v00, v01, v10, v11;
    if (TRANS) {
        const float* base = feat + (size_t)b * HWSZ * CFEAT;
        v00 = base[((size_t)(y0 * FW + x0)) * CFEAT + c];
        v01 = base[((size_t)(y0 * FW + x1i)) * CFEAT + c];
        v10 = base[((size_t)(y1i * FW + x0)) * CFEAT + c];
        v11 = base[((size_t)(y1i * FW + x1i)) * CFEAT + c];
    } else {
        const float* base = feat + ((size_t)(b * CFEAT + c)) * HWSZ;
        v00 = base[y0 * FW + x0];
        v01 = base[y0 * FW + x1i];
        v10 = base[y1i * FW + x0];
        v11 = base[y1i * FW + x1i];
    }
    float v = hy * hx * v00 + hy * lx * v01 + ly * hx * v10 + ly * lx * v11;
    return valid ? v : 0.f;
}

// ---------------- RoIAlign -> fp32 x (fallback path) ----------------
template<bool TRANS>
__global__ __launch_bounds__(256) void roi_k(const float* __restrict__ feat,
                                             const float* __restrict__ boxes,
                                             float* __restrict__ xout) {
    int pp = blockIdx.x, r = blockIdx.y, c = threadIdx.x;
    int b = r >> 9;
    const float* bx = boxes + (size_t)r * 4;
    float x1 = bx[0] * 0.25f, y1 = bx[1] * 0.25f, x2 = bx[2] * 0.25f, y2 = bx[3] * 0.25f;
    float rw = fmaxf(x2 - x1, 1.0f), rh = fmaxf(y2 - y1, 1.0f);
    float bw = rw / 7.0f, bh = rh / 7.0f;
    int py = pp / 7, px = pp % 7;
    float acc = 0.f;
#pragma unroll
    for (int sy = 0; sy < 2; ++sy)
#pragma unroll
        for (int sx = 0; sx < 2; ++sx)
            acc += bil_sample<TRANS>(feat, b, c,
                                     y1 + ((float)py + 0.25f + 0.5f * (float)sy) * bh,
                                     x1 + ((float)px + 0.25f + 0.5f * (float)sx) * bw);
    xout[(size_t)r * INDIM + pp * 256 + c] = acc * 0.25f;
}

// ---------------- RoIAlign -> split bf16 planes, float4-vectorized ----------------
__global__ __launch_bounds__(256) void roi_split4_k(const float* __restrict__ feat,
                                                    const float* __restrict__ boxes,
                                                    unsigned short* __restrict__ Ap) {
    int tid = threadIdx.x;
    int g = tid >> 7;              // roi within block
    int binhalf = (tid >> 6) & 1;  // bin parity
    int cl = tid & 63;             // channels 4cl..4cl+3
    int r = blockIdx.x * 2 + g;
    int b = r >> 9;
    const float* bx = boxes + (size_t)r * 4;
    float x1 = bx[0] * 0.25f, y1 = bx[1] * 0.25f, x2 = bx[2] * 0.25f, y2 = bx[3] * 0.25f;
    float rw = fmaxf(x2 - x1, 1.0f), rh = fmaxf(y2 - y1, 1.0f);
    float bw = rw / 7.0f, bh = rh / 7.0f;
    int mt = r >> 7, rr = r & 127;
    size_t pstr = (size_t)8 * KKT1 * 4096;
    const float* base = feat + (size_t)b * HWSZ * CFEAT;
    for (int pp = binhalf; pp < 49; pp += 2) {
        int py = pp / 7, px = pp % 7;
        float ax = 0.f, ay = 0.f, az = 0.f, aw = 0.f;
#pragma unroll
        for (int sy = 0; sy < 2; ++sy) {
#pragma unroll
            for (int sx = 0; sx < 2; ++sx) {
                float yy = y1 + ((float)py + 0.25f + 0.5f * (float)sy) * bh;
                float xx = x1 + ((float)px + 0.25f + 0.5f * (float)sx) * bw;
                bool valid = (yy > -1.f) && (yy < (float)FH) && (xx > -1.f) && (xx < (float)FW);
                float yc = fminf(fmaxf(yy, 0.f), (float)(FH - 1));
                float xc = fminf(fmaxf(xx, 0.f), (float)(FW - 1));
                int y0 = (int)floorf(yc), x0 = (int)floorf(xc);
                int y1i = min(y0 + 1, FH - 1), x1i = min(x0 + 1, FW - 1);
                float ly = yc - (float)y0, lx = xc - (float)x0;
                float hy = 1.f - ly, hx = 1.f - lx;
                float w00 = hy * hx, w01 = hy * lx, w10 = ly * hx, w11 = ly * lx;
                if (!valid) { w00 = w01 = w10 = w11 = 0.f; }
                float4 v00 = ((const float4*)(base + (size_t)(y0 * FW + x0) * CFEAT))[cl];
                float4 v01 = ((const float4*)(base + (size_t)(y0 * FW + x1i) * CFEAT))[cl];
                float4 v10 = ((const float4*)(base + (size_t)(y1i * FW + x0) * CFEAT))[cl];
                float4 v11 = ((const float4*)(base + (size_t)(y1i * FW + x1i) * CFEAT))[cl];
                ax += w00 * v00.x + w01 * v01.x + w10 * v10.x + w11 * v11.x;
                ay += w00 * v00.y + w01 * v01.y + w10 * v10.y + w11 * v11.y;
                az += w00 * v00.z + w01 * v01.z + w10 * v10.z + w11 * v11.z;
                aw += w00 * v00.w + w01 * v01.w + w10 * v10.w + w11 * v11.w;
            }
        }
        ax *= 0.25f; ay *= 0.25f; az *= 0.25f; aw *= 0.25f;
        ushort4 h4, m4, l4;
        split3(ax, h4.x, m4.x, l4.x);
        split3(ay, h4.y, m4.y, l4.y);
        split3(az, h4.z, m4.z, l4.z);
        split3(aw, h4.w, m4.w, l4.w);
        int k0 = pp * 256 + cl * 4;
        int kk = k0 >> 5;
        size_t tile = ((size_t)mt * KKT1 + kk) * 4096 + rr * 32 + (k0 & 31);
        *(ushort4*)&Ap[tile] = h4;
        *(ushort4*)&Ap[tile + pstr] = m4;
        *(ushort4*)&Ap[tile + 2 * pstr] = l4;
    }
}

// ---------------- weight split + transpose into tiled planes ----------------
template<bool PERM>
__global__ __launch_bounds__(256) void wsplit_k(const float* __restrict__ W,
                                                unsigned short* __restrict__ out, int kkT) {
    __shared__ float tf[32][132];
    int nt = blockIdx.x, kk = blockIdx.y;
    int t = threadIdx.x;
    int kloc = t >> 3;
    int f4 = t & 7;
    int krow;
    if (PERM) krow = ((kk & 7) * 32 + kloc) * 49 + (kk >> 3);
    else krow = kk * 32 + kloc;
    const float* src = W + (size_t)krow * 1024 + nt * 128;
#pragma unroll
    for (int q = 0; q < 4; ++q) {
        float4 v = *(const float4*)(src + (f4 + q * 8) * 4);
        *(float4*)&tf[kloc][(f4 + q * 8) * 4] = v;
    }
    __syncthreads();
    int r = t >> 1;
    size_t tileBase = ((size_t)nt * kkT + kk) * 4096;
    size_t pstr = (size_t)8 * kkT * 4096;
#pragma unroll
    for (int cc = 0; cc < 2; ++cc) {
        int c = (t & 1) * 2 + cc;
        ushort8v hv, mv, lv;
#pragma unroll
        for (int e = 0; e < 8; ++e) {
            unsigned short h, m, l;
            split3(tf[c * 8 + e][r], h, m, l);
            hv[e] = h; mv[e] = m; lv[e] = l;
        }
        size_t o = tileBase + r * 32 + c * 8;
        *(ushort8v*)&out[o] = hv;
        *(ushort8v*)&out[o + pstr] = mv;
        *(ushort8v*)&out[o + 2 * pstr] = lv;
    }
}

// ---------------- head weights (Wc|Wr, zero-padded to 128 cols) -> planes ----------------
__global__ __launch_bounds__(256) void wsplit_head_k(const float* __restrict__ Wc,
                                                     const float* __restrict__ Wr,
                                                     unsigned short* __restrict__ out) {
    int kk = blockIdx.x, t = threadIdx.x;
    int r = t >> 1;
    int k0 = (t & 1) * 16;
    size_t pstr = (size_t)KKT2 * 4096;
    for (int e = 0; e < 16; ++e) {
        int k = k0 + e;
        int krow = kk * 32 + k;
        float v = 0.f;
        if (r < 81) v = Wc[(size_t)krow * 81 + r];
        else if (r < 85) v = Wr[(size_t)krow * 4 + (r - 81)];
        unsigned short h, m, l;
        split3(v, h, m, l);
        size_t o = (size_t)kk * 4096 + r * 32 + k;
        out[o] = h;
        out[o + pstr] = m;
        out[o + 2 * pstr] = l;
    }
}

// ---------------- MFMA GEMM: 256x128 tile, 512 thr (8 waves), A+B double-buffered ----------------
// 1 block/CU (144 KB LDS), grid = 32 tiles x SPLITK = 256 = exactly one per CU.
// Per kk: stage next kk (9 loads/thread) -> s_waitcnt vmcnt(9) (prior batch landed,
// new batch stays in flight across both barriers) -> 96 MFMA/wave -> barrier.
// 8 waves/CU = 2/SIMD keeps MFMA+LDS pipes co-scheduled (r7's 4-wave failure avoided).
#define TERM16(AF) { _Pragma("unroll") for (int i = 0; i < 4; ++i) _Pragma("unroll") \
    for (int j = 0; j < 4; ++j) acc[i][j] = __builtin_amdgcn_mfma_f32_16x16x32_bf16(AF[i], bf[j], acc[i][j], 0, 0, 0); }

__global__ __launch_bounds__(512) void gemm_mfma_k(const unsigned short* __restrict__ Ap,
                                                   const unsigned short* __restrict__ Bp,
                                                   float* __restrict__ partial,
                                                   int kkT, int kkPer, int NT, int N) {
    __shared__ unsigned short sA[2][3][8192];   // 96 KB: [buf][plane][2 mt-tiles x 4096]
    __shared__ unsigned short sB[2][3][4096];   // 48 KB
    int tid = threadIdx.x;
    // bijective XCD swizzle (grid % 8 == 0 for all call sites)
    int phys = blockIdx.x;
    int logical = (phys & 7) * (gridDim.x >> 3) + (phys >> 3);
    int tpc = 4 * NT;                 // tiles per ck: 4 mt-pairs x NT
    int xy = logical % tpc;
    int ck = logical / tpc;
    int mtb = xy & 3;                 // mt-pair index (rows mtb*256..+255)
    int nt = xy >> 2;
    int kk0 = ck * kkPer;
    size_t pstrA = (size_t)8 * kkT * 4096 * 2;    // bytes
    size_t pstrB = (size_t)NT * kkT * 4096 * 2;   // bytes
    const char* aBase = (const char*)(Ap + (size_t)(mtb * 2) * kkT * 4096);
    const char* bBase = (const char*)(Bp + (size_t)nt * kkT * 4096);

    float4v acc[4][4];
#pragma unroll
    for (int i = 0; i < 4; ++i)
#pragma unroll
        for (int j = 0; j < 4; ++j) acc[i][j] = (float4v){0.f, 0.f, 0.f, 0.f};

    int lane = tid & 63, wv = tid >> 6;     // 8 waves
    int wr = wv >> 1, wc = wv & 1;          // 4x2 grid of 64x64 wave tiles
    int ln = lane & 15;
    int q = lane >> 4;
    int qs = (q ^ (ln ^ (ln >> 2))) & 3;
    // A: row g = wr*64 + f*16 + ln within 256; tile = wr>>1, row_in = (wr&1)*64 + f*16 + ln
    int aoffE = (wr >> 1) * 4096 + ((wr & 1) * 64 + ln) * 32 + qs * 8;   // + f*512
    int boffE = (wc * 64 + ln) * 32 + qs * 8;                            // + f*512

    int o0 = tid * 16;            // 0..8191: one 8KB tile per pass (512 thr x 16B)
    int s0 = swz8k(o0);

    auto stage = [&](int buf, int kk) {
#pragma unroll
        for (int p = 0; p < 3; ++p) {
            const char* at = aBase + (size_t)p * pstrA + (size_t)kk * 8192;
            gload_lds16(at + s0, (char*)sA[buf][p] + o0);
            gload_lds16(at + (size_t)kkT * 8192 + s0, (char*)sA[buf][p] + 8192 + o0);
            const char* bt = bBase + (size_t)p * pstrB + (size_t)kk * 8192;
            gload_lds16(bt + s0, (char*)sB[buf][p] + o0);
        }
    };

    stage(0, kk0);
    for (int it = 0; it < kkPer; ++it) {
        int cur = it & 1;
        if (it + 1 < kkPer) {
            stage(cur ^ 1, kk0 + it + 1);      // 9 loads: stay in flight across barriers
            asm volatile("s_waitcnt vmcnt(9)" ::: "memory");   // prior batch landed
        } else {
            asm volatile("s_waitcnt vmcnt(0)" ::: "memory");
        }
        __builtin_amdgcn_s_barrier();
        __builtin_amdgcn_sched_barrier(0);
        short8v af[3][4];
#pragma unroll
        for (int p = 0; p < 3; ++p)
#pragma unroll
            for (int f = 0; f < 4; ++f)
                af[p][f] = *(const short8v*)&sA[cur][p][aoffE + f * 512];
        short8v bf[4];
#pragma unroll
        for (int f = 0; f < 4; ++f) bf[f] = *(const short8v*)&sB[cur][0][boffE + f * 512];
        TERM16(af[0]); TERM16(af[1]); TERM16(af[2]);
#pragma unroll
        for (int f = 0; f < 4; ++f) bf[f] = *(const short8v*)&sB[cur][1][boffE + f * 512];
        TERM16(af[0]); TERM16(af[1]);
#pragma unroll
        for (int f = 0; f < 4; ++f) bf[f] = *(const short8v*)&sB[cur][2][boffE + f * 512];
        TERM16(af[0]);
        __builtin_amdgcn_sched_barrier(0);
        __builtin_amdgcn_s_barrier();          // readers done before next overwrite
    }
    float* outp = partial + (size_t)ck * 1024 * N;
    int row0 = mtb * 256 + wr * 64 + (lane >> 4) * 4;
    int col = nt * 128 + wc * 64 + ln;
#pragma unroll
    for (int i = 0; i < 4; ++i)
#pragma unroll
        for (int j = 0; j < 4; ++j)
#pragma unroll
            for (int qq = 0; qq < 4; ++qq)
                outp[(size_t)(row0 + i * 16 + qq) * N + col + j * 16] = acc[i][j][qq];
}

// ---------------- split-K reduce + bias + relu -> split planes (KKT2 layout) ----------------
template<int NS>
__global__ void reduce8_k(const float* __restrict__ partial, const float* __restrict__ bias,
                          unsigned short* __restrict__ planes) {
    int i = blockIdx.x * 256 + threadIdx.x;
    float s = 0.f;
#pragma unroll
    for (int c = 0; c < NS; ++c) s += partial[((size_t)c << 20) + i];
    s += bias[i & 1023];
    s = fmaxf(s, 0.f);
    int m = i >> 10, n = i & 1023;
    int mt = m >> 7, rr = m & 127, kk = n >> 5;
    unsigned short h, mm_, l;
    split3(s, h, mm_, l);
    size_t tile = ((size_t)mt * KKT2 + kk) * 4096 + rr * 32 + (n & 31);
    size_t pstr = (size_t)8 * KKT2 * 4096;
    planes[tile] = h;
    planes[tile + pstr] = mm_;
    planes[tile + 2 * pstr] = l;
}

// ---------------- head finalize: sum 8 slices + bias -> logits/deltas ----------------
__global__ void head_fin_k(const float* __restrict__ partial, const float* __restrict__ bc,
                           const float* __restrict__ br, float* __restrict__ logits,
                           float* __restrict__ deltas, int write_logits) {
    int idx = blockIdx.x * 256 + threadIdx.x;
    if (idx >= 1024 * 85) return;
    int m = idx / 85, col = idx - m * 85;
    float s = 0.f;
#pragma unroll
    for (int c = 0; c < 8; ++c) s += partial[(size_t)c * 131072 + m * 128 + col];
    if (col < 81) {
        if (write_logits) logits[(size_t)m * NCLS + col] = s + bc[col];
    } else {
        deltas[(size_t)m * 4 + (col - 81)] = s + br[col - 81];
    }
}

// ---------------- old fp32 GEMM (fallback) ----------------
template<bool PERM>
__global__ __launch_bounds__(256) void gemm_k(const float* __restrict__ A,
                                              const float* __restrict__ Bm,
                                              float* __restrict__ partial,
                                              int K_total, int Kchunk) {
    const int M = 1024, N = 1024;
    __shared__ float As[2][16][128];
    __shared__ float Bs[2][16][64];
    int tid = threadIdx.x;
    int mb = blockIdx.x & 7;
    int nb = blockIdx.x >> 3;
    int ck = blockIdx.y;
    int k0 = ck * Kchunk;
    int am = tid >> 1;
    int ak = (tid & 1) * 8;
    int bk = tid >> 4;
    int bn = (tid & 15) * 4;
    int ty = tid >> 4, tx = tid & 15;
    const float* Aptr = A + (size_t)(mb * 128 + am) * K_total + k0 + ak;

    float acc[8][4];
#pragma unroll
    for (int i = 0; i < 8; ++i)
#pragma unroll
        for (int j = 0; j < 4; ++j) acc[i][j] = 0.f;

    auto bRowPtr = [&](int kk) -> const float* {
        int row = PERM ? ((kk & 255) * 49 + (kk >> 8)) : kk;
        return Bm + (size_t)row * N + nb * 64 + bn;
    };

    int T = Kchunk / 16;
    float4 a0 = *(const float4*)(Aptr);
    float4 a1 = *(const float4*)(Aptr + 4);
    float4 b0 = *(const float4*)bRowPtr(k0 + bk);
    As[0][ak + 0][am] = a0.x; As[0][ak + 1][am] = a0.y; As[0][ak + 2][am] = a0.z; As[0][ak + 3][am] = a0.w;
    As[0][ak + 4][am] = a1.x; As[0][ak + 5][am] = a1.y; As[0][ak + 6][am] = a1.z; As[0][ak + 7][am] = a1.w;
    *(float4*)&Bs[0][bk][bn] = b0;
    __syncthreads();

    int p = 0;
    for (int t = 0; t < T; ++t) {
        if (t + 1 < T) {
            a0 = *(const float4*)(Aptr + (t + 1) * 16);
            a1 = *(const float4*)(Aptr + (t + 1) * 16 + 4);
            b0 = *(const float4*)bRowPtr(k0 + (t + 1) * 16 + bk);
        }
#pragma unroll
        for (int k = 0; k < 16; ++k) {
            float4 av0 = *(const float4*)&As[p][k][ty * 8];
            float4 av1 = *(const float4*)&As[p][k][ty * 8 + 4];
            float4 bv = *(const float4*)&Bs[p][k][tx * 4];
            float ar[8] = {av0.x, av0.y, av0.z, av0.w, av1.x, av1.y, av1.z, av1.w};
            float br_[4] = {bv.x, bv.y, bv.z, bv.w};
#pragma unroll
            for (int i = 0; i < 8; ++i)
#pragma unroll
                for (int j = 0; j < 4; ++j) acc[i][j] = fmaf(ar[i], br_[j], acc[i][j]);
        }
        if (t + 1 < T) {
            __syncthreads();
            int qb = 1 - p;
            As[qb][ak + 0][am] = a0.x; As[qb][ak + 1][am] = a0.y; As[qb][ak + 2][am] = a0.z; As[qb][ak + 3][am] = a0.w;
            As[qb][ak + 4][am] = a1.x; As[qb][ak + 5][am] = a1.y; As[qb][ak + 6][am] = a1.z; As[qb][ak + 7][am] = a1.w;
            *(float4*)&Bs[qb][bk][bn] = b0;
            __syncthreads();
            p = qb;
        }
    }
    float* out = partial + ((size_t)ck * M + mb * 128 + ty * 8) * N + nb * 64 + tx * 4;
#pragma unroll
    for (int i = 0; i < 8; ++i) {
        float4 v = make_float4(acc[i][0], acc[i][1], acc[i][2], acc[i][3]);
        *(float4*)(out + (size_t)i * N) = v;
    }
}

__global__ void reduce4_k(const float* __restrict__ partial, const float* __restrict__ bias,
                          float* __restrict__ out) {
    const int MN = 1024 * 1024;
    int i = blockIdx.x * 256 + threadIdx.x;
    if (i >= MN) return;
    float s = partial[i] + partial[(size_t)MN + i] + partial[(size_t)2 * MN + i] + partial[(size_t)3 * MN + i];
    s += bias[i & 1023];
    out[i] = fmaxf(s, 0.f);
}

// ---------------- cls + reg heads (fallback) ----------------
__global__ __launch_bounds__(128) void head_k(const float* __restrict__ h,
                                              const float* __restrict__ Wc, const float* __restrict__ bc,
                                              const float* __restrict__ Wr, const float* __restrict__ br,
                                              float* __restrict__ logits, float* __restrict__ deltas,
                                              int write_logits) {
    __shared__ float hs[1024];
    int m = blockIdx.x;
    int tid = threadIdx.x;
    const float4* hp = (const float4*)(h + (size_t)m * 1024);
    ((float4*)hs)[tid] = hp[tid];
    ((float4*)hs)[tid + 128] = hp[tid + 128];
    __syncthreads();
    int j = tid;
    if (j < 85) {
        bool is_cls = j < 81;
        const float* Wp = is_cls ? Wc : Wr;
        int stride = is_cls ? 81 : 4;
        int col = is_cls ? j : j - 81;
        float s0 = 0.f, s1 = 0.f, s2 = 0.f, s3 = 0.f;
        for (int k = 0; k < 1024; k += 4) {
            s0 = fmaf(hs[k + 0], Wp[(k + 0) * stride + col], s0);
            s1 = fmaf(hs[k + 1], Wp[(k + 1) * stride + col], s1);
            s2 = fmaf(hs[k + 2], Wp[(k + 2) * stride + col], s2);
            s3 = fmaf(hs[k + 3], Wp[(k + 3) * stride + col], s3);
        }
        float s = (s0 + s1) + (s2 + s3);
        if (is_cls) {
            if (write_logits) logits[(size_t)m * NCLS + col] = s + bc[col];
        } else {
            deltas[(size_t)m * 4 + col] = s + br[col];
        }
    }
}

// ---------------- box decode ----------------
__global__ void decode_k(const float* __restrict__ prev, const float* __restrict__ deltas,
                         float* __restrict__ nxt, float wx, float wy, float ww, float wh) {
    int r = blockIdx.x * 256 + threadIdx.x;
    if (r >= NROI) return;
    const float* p = prev + (size_t)r * 4;
    const float* d = deltas + (size_t)r * 4;
    float px1 = p[0], py1 = p[1], px2 = p[2], py2 = p[3];
    float pw = fmaxf(px2 - px1, 1e-6f), ph = fmaxf(py2 - py1, 1e-6f);
    float pcx = px1 + 0.5f * pw, pcy = py1 + 0.5f * ph;
    float dx = d[0] * wx, dy = d[1] * wy;
    float dw = fminf(d[2] * ww, CLIPV);
    float dh = fminf(d[3] * wh, CLIPV);
    float gx = dx * pw + pcx, gy = dy * ph + pcy;
    float gw = expf(dw) * pw, gh = expf(dh) * ph;
    nxt[(size_t)r * 4 + 0] = fminf(fmaxf(gx - 0.5f * gw, 0.f), 800.f);
    nxt[(size_t)r * 4 + 1] = fminf(fmaxf(gy - 0.5f * gh, 0.f), 800.f);
    nxt[(size_t)r * 4 + 2] = fminf(fmaxf(gx + 0.5f * gw, 0.f), 800.f);
    nxt[(size_t)r * 4 + 3] = fminf(fmaxf(gy + 0.5f * gh, 0.f), 800.f);
}

// ---------------- softmax over 81 classes ----------------
__global__ __launch_bounds__(128) void softmax_k(const float* __restrict__ logits, float* __restrict__ probs) {
    __shared__ float red[128];
    int m = blockIdx.x;
    int tid = threadIdx.x;
    float v = (tid < NCLS) ? logits[(size_t)m * NCLS + tid] : -FLT_MAX;
    red[tid] = v;
    __syncthreads();
    for (int o = 64; o; o >>= 1) {
        if (tid < o) red[tid] = fmaxf(red[tid], red[tid + o]);
        __syncthreads();
    }
    float mx = red[0];
    __syncthreads();
    float e = (tid < NCLS) ? expf(v - mx) : 0.f;
    red[tid] = e;
    __syncthreads();
    for (int o = 64; o; o >>= 1) {
        if (tid < o) red[tid] += red[tid + o];
        __syncthreads();
    }
    float s = red[0];
    if (tid < NCLS) probs[(size_t)m * NCLS + tid] = e / s;
}

// ---------------- postprocess: score build ----------------
__global__ void build_scores_k(const float* __restrict__ probs, const float* __restrict__ boxes,
                               float* __restrict__ sc, int* __restrict__ vcount) {
    int f = blockIdx.x * 256 + threadIdx.x;
    if (f >= NB * NCAND) return;
    int b = f / NCAND, ff = f % NCAND;
    int rr = ff / 80, cls = ff % 80 + 1;
    int row = b * NPROP + rr;
    const float* bx = boxes + (size_t)row * 4;
    bool ok = (bx[2] - bx[0] >= 1.f) && (bx[3] - bx[1] >= 1.f);
    float p = probs[(size_t)row * NCLS + cls];
    float s = (p > 0.05f && ok) ? p : -1.0f;
    sc[f] = s;
    if (s > 0.f) atomicAdd(&vcount[b], 1);
}

// ---------------- pivot search (only when >4096 valid) ----------------
__global__ __launch_bounds__(1024) void find_pivot_k(const float* __restrict__ sc,
                                                     const int* __restrict__ vcount,
                                                     float* __restrict__ pivot) {
    int b = blockIdx.x;
    const float* s = sc + (size_t)b * NCAND;
    __shared__ int tot;
    int V = vcount[b];
    if (V <= CAP) {
        if (threadIdx.x == 0) pivot[b] = 0.f;
        return;
    }
    unsigned u = 0;
    for (int bit = 30; bit >= 0; --bit) {
        unsigned cand = u | (1u << bit);
        float cf = __uint_as_float(cand);
        if (threadIdx.x == 0) tot = 0;
        __syncthreads();
        int cnt = 0;
        for (int i = threadIdx.x; i < NCAND; i += 1024) cnt += (s[i] >= cf) ? 1 : 0;
        for (int o = 32; o; o >>= 1) cnt += __shfl_down(cnt, o);
        if ((threadIdx.x & 63) == 0) atomicAdd(&tot, cnt);
        __syncthreads();
        if (tot >= NSEL) u = cand;
        __syncthreads();
    }
    if (threadIdx.x == 0) pivot[b] = __uint_as_float(u);
}

// ---------------- compact candidates ----------------
__global__ void compact_k(const float* __restrict__ sc, const float* __restrict__ pivot,
                          float* __restrict__ ckey, int* __restrict__ cidx, int* __restrict__ ccount) {
    int f = blockIdx.x * 256 + threadIdx.x;
    if (f >= NB * NCAND) return;
    int b = f / NCAND, ff = f % NCAND;
    float s = sc[f];
    float pv = pivot[b];
    if (s > 0.f && s >= pv) {
        int slot = atomicAdd(&ccount[b], 1);
        if (slot < CAP) {
            ckey[(size_t)b * CAP + slot] = s;
            cidx[(size_t)b * CAP + slot] = ff;
        }
    }
}

// ---------------- bitonic sort + selection ----------------
__global__ __launch_bounds__(1024) void sort_select_k(const float* __restrict__ ckey,
                                                      const int* __restrict__ cidx,
                                                      const int* __restrict__ ccount,
                                                      const float* __restrict__ boxes,
                                                      float* __restrict__ selb, float* __restrict__ seloff,
                                                      float* __restrict__ selsc, int* __restrict__ sellab,
                                                      unsigned long long* __restrict__ vmask) {
    int b = blockIdx.x;
    __shared__ float ks[CAP];
    __shared__ int is[CAP];
    __shared__ float rmax[1024];
    int cnt = min(ccount[b], CAP);
    for (int i = threadIdx.x; i < CAP; i += 1024) {
        if (i < cnt) {
            ks[i] = ckey[(size_t)b * CAP + i];
            is[i] = cidx[(size_t)b * CAP + i];
        } else {
            ks[i] = -FLT_MAX;
            is[i] = 0x7FFFFFFF;
        }
    }
    __syncthreads();
    for (int k = 2; k <= CAP; k <<= 1) {
        for (int j = k >> 1; j > 0; j >>= 1) {
            for (int t = threadIdx.x; t < CAP; t += 1024) {
                int l = t ^ j;
                if (l > t) {
                    bool up = ((t & k) == 0);
                    float a = ks[t], bb = ks[l];
                    int ia = is[t], ib = is[l];
                    bool a_first = (a > bb) || (a == bb && ia < ib);
                    bool doswap = up ? !a_first : a_first;
                    if (doswap) {
                        ks[t] = bb; ks[l] = a;
                        is[t] = ib; is[l] = ia;
                    }
                }
            }
            __syncthreads();
        }
    }
    float lm = -FLT_MAX;
    for (int i = threadIdx.x; i < NSEL; i += 1024) {
        if (ks[i] > 0.f) {
            const float* bb = boxes + (size_t)(b * NPROP + is[i] / 80) * 4;
            lm = fmaxf(lm, fmaxf(fmaxf(bb[0], bb[1]), fmaxf(bb[2], bb[3])));
        }
    }
    rmax[threadIdx.x] = lm;
    __syncthreads();
    for (int o = 512; o; o >>= 1) {
        if (threadIdx.x < o) rmax[threadIdx.x] = fmaxf(rmax[threadIdx.x], rmax[threadIdx.x + o]);
        __syncthreads();
    }
    float maxb = (rmax[0] > -FLT_MAX) ? rmax[0] : 0.f;
    __syncthreads();
    for (int pass = 0; pass < 2; ++pass) {
        int i = pass * 1024 + threadIdx.x;
        bool v = ks[i] > 0.f;
        int idx = is[i];
        int rr = idx / 80;
        int cls = idx % 80 + 1;
        float b0 = 0.f, b1 = 0.f, b2 = 0.f, b3 = 0.f, offv = 0.f;
        if (v) {
            const float* bb = boxes + (size_t)(b * NPROP + rr) * 4;
            b0 = bb[0]; b1 = bb[1]; b2 = bb[2]; b3 = bb[3];
            offv = (maxb + 1.f) * (float)cls;
        }
        float* sb = selb + ((size_t)b * NSEL + i) * 4;
        sb[0] = b0; sb[1] = b1; sb[2] = b2; sb[3] = b3;
        float* so = seloff + ((size_t)b * NSEL + i) * 4;
        so[0] = b0 + offv; so[1] = b1 + offv; so[2] = b2 + offv; so[3] = b3 + offv;
        selsc[(size_t)b * NSEL + i] = v ? ks[i] : 0.f;
        sellab[(size_t)b * NSEL + i] = cls;
        unsigned long long m = __ballot(v);
        if ((threadIdx.x & 63) == 0) vmask[b * 32 + pass * 16 + (threadIdx.x >> 6)] = m;
    }
}

// ---------------- suppression bitmask (upper triangle only) ----------------
__global__ __launch_bounds__(256) void sup_k(const float* __restrict__ seloff,
                                             const float* __restrict__ selsc,
                                             unsigned long long* __restrict__ sup) {
    int b = blockIdx.y;
    int wave = threadIdx.x >> 6;
    int lane = threadIdx.x & 63;
    int pair = blockIdx.x * 4 + wave;
    int i = pair >> 5;
    int w = pair & 31;
    int j = w * 64 + lane;
    unsigned long long m = 0;
    if (w >= (i >> 6) && selsc[(size_t)b * NSEL + i] > 0.f) {
        const float* oi = seloff + ((size_t)b * NSEL + i) * 4;
        const float* oj = seloff + ((size_t)b * NSEL + j) * 4;
        float ax1 = oi[0], ay1 = oi[1], ax2 = oi[2], ay2 = oi[3];
        float bx1 = oj[0], by1 = oj[1], bx2 = oj[2], by2 = oj[3];
        float areaA = (ax2 - ax1) * (ay2 - ay1);
        float areaB = (bx2 - bx1) * (by2 - by1);
        float ltx = fmaxf(ax1, bx1), lty = fmaxf(ay1, by1);
        float rbx = fminf(ax2, bx2), rby = fminf(ay2, by2);
        float iw = fmaxf(rbx - ltx, 0.f), ih = fmaxf(rby - lty, 0.f);
        float inter = iw * ih;
        float iou = inter / (areaA + areaB - inter + 1e-12f);
        m = __ballot(iou > 0.5f);
    }
    if (lane == 0) sup[((size_t)b * NSEL + i) * 32 + w] = m;
}

// ---------------- NMS scan: word-blocked, scalar serial chain, early exit ----------------
__global__ __launch_bounds__(256) void nms_scan_k(const unsigned long long* __restrict__ vmask,
                                                  const unsigned long long* __restrict__ sup,
                                                  const float* __restrict__ selb,
                                                  const float* __restrict__ selsc,
                                                  const int* __restrict__ sellab,
                                                  float* __restrict__ out) {
    int b = blockIdx.x;
    __shared__ unsigned long long keepw[32];
    __shared__ int pref[33];
    int tid = threadIdx.x;
    if (tid < 64) {
        int lane = tid;
        unsigned long long kw = (lane < 32) ? vmask[b * 32 + lane] : 0ull;
        const unsigned long long* supB = sup + (size_t)b * NSEL * 32;
        int kept = 0;
        for (int w = 0; w < 32; ++w) {
            unsigned long long cur = __shfl(kw, w);
            if (cur) {
                unsigned long long R = supB[(size_t)(w * 64 + lane) * 32 + w];
                for (int b0 = 0; b0 < 64; b0 += 8) {
                    unsigned long long r0 = __shfl(R, b0 + 0);
                    unsigned long long r1 = __shfl(R, b0 + 1);
                    unsigned long long r2 = __shfl(R, b0 + 2);
                    unsigned long long r3 = __shfl(R, b0 + 3);
                    unsigned long long r4 = __shfl(R, b0 + 4);
                    unsigned long long r5 = __shfl(R, b0 + 5);
                    unsigned long long r6 = __shfl(R, b0 + 6);
                    unsigned long long r7 = __shfl(R, b0 + 7);
                    unsigned long long hi;
#define NMS_STEP(rr_, dd_) { int bb = b0 + dd_; \
                    hi = (bb == 63) ? 0ull : (~0ull << (bb + 1)); \
                    cur &= ~((0ull - ((cur >> bb) & 1ull)) & rr_ & hi); }
                    NMS_STEP(r0, 0) NMS_STEP(r1, 1) NMS_STEP(r2, 2) NMS_STEP(r3, 3)
                    NMS_STEP(r4, 4) NMS_STEP(r5, 5) NMS_STEP(r6, 6) NMS_STEP(r7, 7)
#undef NMS_STEP
                }
                kept += __popcll(cur);
                if (lane == w) kw = cur;
                if (kept >= DETS) break;
                int v = lane & 31;
                int h = lane >> 5;
                unsigned long long acc = 0;
                const unsigned long long* rowb = supB + (size_t)(w * 64 + h) * 32 + v;
#pragma unroll 8
                for (int t = 0; t < 32; ++t) {
                    unsigned long long msk = 0ull - ((cur >> (h + 2 * t)) & 1ull);
                    acc |= rowb[(size_t)(2 * t) * 32] & msk;
                }
                acc |= __shfl_xor(acc, 32);
                if (lane < 32 && lane > w) kw &= ~acc;
            }
        }
        if (lane < 32) keepw[lane] = kw;
    }
    __syncthreads();
    if (tid == 0) {
        int s = 0;
        for (int w = 0; w < 32; ++w) { pref[w] = s; s += __popcll(keepw[w]); }
        pref[32] = s;
    }
    __syncthreads();
    for (int i = tid; i < 600; i += 256) {
        if (i < 400) out[b * 400 + i] = 0.f;
        else if (i < 500) out[800 + b * 100 + (i - 400)] = 0.f;
        else out[1000 + b * 100 + (i - 500)] = 0.f;
    }
    __syncthreads();
    for (int e = tid; e < NSEL; e += 256) {
        int w = e >> 6;
        unsigned long long kw = keepw[w];
        if ((kw >> (e & 63)) & 1ull) {
            int rank = pref[w] + __popcll(kw & ((1ull << (e & 63)) - 1ull));
            if (rank < DETS) {
                const float* sb = selb + ((size_t)b * NSEL + e) * 4;
                out[b * 400 + rank * 4 + 0] = sb[0];
                out[b * 400 + rank * 4 + 1] = sb[1];
                out[b * 400 + rank * 4 + 2] = sb[2];
                out[b * 400 + rank * 4 + 3] = sb[3];
                out[800 + b * 100 + rank] = selsc[(size_t)b * NSEL + e];
                out[1000 + b * 100 + rank] = (float)sellab[(size_t)b * NSEL + e];
            }
        }
    }
}

extern "C" void kernel_launch(void* const* d_in, const int* in_sizes, int n_in,
                              void* d_out, int out_size, void* d_ws, size_t ws_size,
                              hipStream_t stream) {
    const float* features = (const float*)d_in[0];
    const float* proposals = (const float*)d_in[1];
    const float* W1 = (const float*)d_in[2];
    const float* b1 = (const float*)d_in[3];
    const float* W2 = (const float*)d_in[4];
    const float* b2 = (const float*)d_in[5];
    const float* Wc = (const float*)d_in[6];
    const float* bc = (const float*)d_in[7];
    const float* Wr = (const float*)d_in[8];
    const float* br = (const float*)d_in[9];

    char* ws = (char*)d_ws;
    size_t off = 0;
    auto alloc = [&](size_t bytes) -> void* {
        void* p = ws + off;
        off += (bytes + 255) & ~(size_t)255;
        return p;
    };

    float* logits = (float*)alloc((size_t)NROI * NCLS * 4);
    float* probs = (float*)alloc((size_t)NROI * NCLS * 4);
    float* deltas = (float*)alloc((size_t)NROI * 4 * 4);
    float* cur1 = (float*)alloc((size_t)NROI * 4 * 4);
    float* cur2 = (float*)alloc((size_t)NROI * 4 * 4);
    float* cur3 = (float*)alloc((size_t)NROI * 4 * 4);
    float* sc = (float*)alloc((size_t)NB * NCAND * 4);
    float* ckey = (float*)alloc((size_t)NB * CAP * 4);
    int* cidx = (int*)alloc((size_t)NB * CAP * 4);
    int* counters = (int*)alloc(256);
    float* pivot = (float*)(counters + 4);
    float* selb = (float*)alloc((size_t)NB * NSEL * 4 * 4);
    float* seloff = (float*)alloc((size_t)NB * NSEL * 4 * 4);
    float* selsc = (float*)alloc((size_t)NB * NSEL * 4);
    int* sellab = (int*)alloc((size_t)NB * NSEL * 4);
    unsigned long long* vmask = (unsigned long long*)alloc((size_t)NB * 32 * 8);
    unsigned long long* sup = (unsigned long long*)alloc((size_t)NB * NSEL * 32 * 8);

    const float stds[3][4] = {{0.1f, 0.1f, 0.2f, 0.2f},
                              {0.05f, 0.05f, 0.1f, 0.1f},
                              {0.033f, 0.033f, 0.067f, 0.067f}};
    float* curbufs[3] = {cur1, cur2, cur3};
    const float* curp = proposals;

    size_t planes1 = (size_t)3 * 8 * KKT1 * 4096 * 2;   // 77 MB
    size_t planes2 = (size_t)3 * 8 * KKT2 * 4096 * 2;   // 6.3 MB
    size_t planesH = (size_t)3 * 1 * KKT2 * 4096 * 2;   // 0.79 MB
    size_t mfma_need = planes1 * 2 + planes2 * 3 + planesH +
                       (size_t)SPLITK * (1 << 20) * 4 +
                       (size_t)NB * HWSZ * CFEAT * 4 + 65536;

    zero_ints_k<<<1, 64, 0, stream>>>(counters, 4);

    if (off + mfma_need <= ws_size) {
        // ================= MFMA split-bf16 path =================
        unsigned short* Ap1 = (unsigned short*)alloc(planes1);
        unsigned short* Bp1 = (unsigned short*)alloc(planes1);
        unsigned short* h1p = (unsigned short*)alloc(planes2);
        unsigned short* W2Tp = (unsigned short*)alloc(planes2);
        unsigned short* h2p = (unsigned short*)alloc(planes2);
        unsigned short* Whp = (unsigned short*)alloc(planesH);
        float* partial = (float*)alloc((size_t)SPLITK * (1 << 20) * 4);
        float* featT = (float*)alloc((size_t)NB * HWSZ * CFEAT * 4);

        transpose_k<<<dim3(1250, 8, 2), dim3(32, 8), 0, stream>>>(features, featT);

        for (int s = 0; s < 3; ++s) {
            roi_split4_k<<<dim3(NROI / 2), 256, 0, stream>>>(featT, curp, Ap1);
            wsplit_k<true><<<dim3(8, KKT1), 256, 0, stream>>>(W1 + (size_t)s * INDIM * FCD, Bp1, KKT1);
            gemm_mfma_k<<<dim3(256), 512, 0, stream>>>(Ap1, Bp1, partial, KKT1, KKT1 / SPLITK, 8, 1024);
            reduce8_k<SPLITK><<<4096, 256, 0, stream>>>(partial, b1 + s * FCD, h1p);
            wsplit_k<false><<<dim3(8, KKT2), 256, 0, stream>>>(W2 + (size_t)s * FCD * FCD, W2Tp, KKT2);
            gemm_mfma_k<<<dim3(256), 512, 0, stream>>>(h1p, W2Tp, partial, KKT2, 4, 8, 1024);
            reduce8_k<8><<<4096, 256, 0, stream>>>(partial, b2 + s * FCD, h2p);
            wsplit_head_k<<<dim3(KKT2), 256, 0, stream>>>(Wc + (size_t)s * FCD * NCLS,
                                                          Wr + (size_t)s * FCD * 4, Whp);
            gemm_mfma_k<<<dim3(32), 512, 0, stream>>>(h2p, Whp, partial, KKT2, 4, 1, 128);
            head_fin_k<<<dim3(340), 256, 0, stream>>>(partial, bc + s * NCLS, br + s * 4,
                                                      logits, deltas, (s == 2) ? 1 : 0);
            decode_k<<<4, 256, 0, stream>>>(curp, deltas, curbufs[s],
                                            stds[s][0], stds[s][1], stds[s][2], stds[s][3]);
            curp = curbufs[s];
        }
    } else {
        // ================= fp32 fallback path =================
        float* x = (float*)alloc((size_t)NROI * INDIM * 4);
        float* partial = (float*)alloc((size_t)4 * 1024 * 1024 * 4);
        float* h1 = (float*)alloc((size_t)NROI * FCD * 4);
        float* h2 = (float*)alloc((size_t)NROI * FCD * 4);
        float* featT = (float*)alloc((size_t)NB * HWSZ * CFEAT * 4);
        bool use_trans = (off <= ws_size);

        if (use_trans)
            transpose_k<<<dim3(1250, 8, 2), dim3(32, 8), 0, stream>>>(features, featT);

        for (int s = 0; s < 3; ++s) {
            if (use_trans)
                roi_k<true><<<dim3(49, 1024), 256, 0, stream>>>(featT, curp, x);
            else
                roi_k<false><<<dim3(49, 1024), 256, 0, stream>>>(features, curp, x);
            gemm_k<true><<<dim3(128, 4), 256, 0, stream>>>(x, W1 + (size_t)s * INDIM * FCD, partial, INDIM, 3136);
            reduce4_k<<<4096, 256, 0, stream>>>(partial, b1 + s * FCD, h1);
            gemm_k<false><<<dim3(128, 4), 256, 0, stream>>>(h1, W2 + (size_t)s * FCD * FCD, partial, FCD, 256);
            reduce4_k<<<4096, 256, 0, stream>>>(partial, b2 + s * FCD, h2);
            head_k<<<1024, 128, 0, stream>>>(h2, Wc + (size_t)s * FCD * NCLS, bc + s * NCLS,
                                             Wr + (size_t)s * FCD * 4, br + s * 4,
                                             logits, deltas, (s == 2) ? 1 : 0);
            decode_k<<<4, 256, 0, stream>>>(curp, deltas, curbufs[s],
                                            stds[s][0], stds[s][1], stds[s][2], stds[s][3]);
            curp = curbufs[s];
        }
    }

    softmax_k<<<1024, 128, 0, stream>>>(logits, probs);
    build_scores_k<<<320, 256, 0, stream>>>(probs, curp, sc, counters);
    find_pivot_k<<<2, 1024, 0, stream>>>(sc, counters, pivot);
    compact_k<<<320, 256, 0, stream>>>(sc, pivot, ckey, cidx, counters + 2);
    sort_select_k<<<2, 1024, 0, stream>>>(ckey, cidx, counters + 2, curp, selb, seloff, selsc, sellab, vmask);
    sup_k<<<dim3(16384, 2), 256, 0, stream>>>(seloff, selsc, sup);
    nms_scan_k<<<2, 256, 0, stream>>>(vmask, sup, selb, selsc, sellab, (float*)d_out);
}

// Round 10
// 1035.161 us; speedup vs baseline: 1.1016x; 1.1016x over previous
//
#include <hip/hip_runtime.h>
#include <float.h>
#include <math.h>

#define NB 2
#define NPROP 512
#define NROI 1024        // NB*NPROP
#define CFEAT 256
#define FH 200
#define FW 200
#define HWSZ 40000
#define INDIM 12544      // 256*49
#define FCD 1024
#define NCLS 81
#define NCAND 40960      // per batch: 512*80
#define CAP 4096
#define NSEL 2048
#define DETS 100
#define CLIPV 4.135166556742356f

#define KKT1 392         // 12544/32
#define KKT2 32          // 1024/32
#define SPLITK 8

typedef __attribute__((ext_vector_type(8))) short short8v;
typedef __attribute__((ext_vector_type(8))) unsigned short ushort8v;
typedef __attribute__((ext_vector_type(4))) float float4v;

// ---------------- helpers: bf16 triple split ----------------
__device__ __forceinline__ unsigned short f2bf(float x) {
    unsigned u = __float_as_uint(x);
    unsigned r = (u + 0x7fffu + ((u >> 16) & 1u)) >> 16;
    return (unsigned short)r;
}
__device__ __forceinline__ float bf2f(unsigned short b) {
    return __uint_as_float(((unsigned)b) << 16);
}
__device__ __forceinline__ void split3(float x, unsigned short& h, unsigned short& m, unsigned short& l) {
    h = f2bf(x);
    float r1 = x - bf2f(h);
    m = f2bf(r1);
    float r2 = r1 - bf2f(m);
    l = f2bf(r2);
}

__device__ __forceinline__ void gload_lds16(const void* g, void* l) {
    __builtin_amdgcn_global_load_lds((const __attribute__((address_space(1))) unsigned int*)g,
                                     (__attribute__((address_space(3))) unsigned int*)l, 16, 0, 0);
}

// swizzle involution on byte offsets within an 8KB tile
__device__ __forceinline__ int swz8k(int o) {
    return o ^ ((((o >> 6) ^ (o >> 8)) & 3) << 4);
}

// ---------------- zero counters ----------------
__global__ void zero_ints_k(int* p, int n) {
    int i = blockIdx.x * blockDim.x + threadIdx.x;
    if (i < n) p[i] = 0;
}

// ---------------- feature transpose NCHW -> NHWC ----------------
__global__ __launch_bounds__(256) void transpose_k(const float* __restrict__ in, float* __restrict__ out) {
    __shared__ float tile[32][33];
    int b = blockIdx.z;
    int hw0 = blockIdx.x * 32;
    int c0 = blockIdx.y * 32;
    int tx = threadIdx.x;
    int ty = threadIdx.y;
#pragma unroll
    for (int i = 0; i < 32; i += 8)
        tile[ty + i][tx] = in[((size_t)(b * CFEAT + c0 + ty + i)) * HWSZ + hw0 + tx];
    __syncthreads();
#pragma unroll
    for (int i = 0; i < 32; i += 8)
        out[((size_t)b * HWSZ + hw0 + ty + i) * CFEAT + c0 + tx] = tile[tx][ty + i];
}

// ---------------- bilinear core (scalar, fallback) ----------------
template<bool TRANS>
__device__ __forceinline__ float bil_sample(const float* __restrict__ feat, int b, int c,
                                            float yy, float xx) {
    bool valid = (yy > -1.f) && (yy < (float)FH) && (xx > -1.f) && (xx < (float)FW);
    float yc = fminf(fmaxf(yy, 0.f), (float)(FH - 1));
    float xc = fminf(fmaxf(xx, 0.f), (float)(FW - 1));
    int y0 = (int)floorf(yc), x0 = (int)floorf(xc);
    int y1i = min(y0 + 1, FH - 1), x1i = min(x0 + 1, FW - 1);
    float ly = yc - (float)y0, lx = xc - (float)x0;
    float hy = 1.f - ly, hx = 1.f - lx;
    float v00, v01, v10, v11;
    if (TRANS) {
        const float* base = feat + (size_t)b * HWSZ * CFEAT;
        v00 = base[((size_t)(y0 * FW + x0)) * CFEAT + c];
        v01 = base[((size_t)(y0 * FW + x1i)) * CFEAT + c];
        v10 = base[((size_t)(y1i * FW + x0)) * CFEAT + c];
        v11 = base[((size_t)(y1i * FW + x1i)) * CFEAT + c];
    } else {
        const float* base = feat + ((size_t)(b * CFEAT + c)) * HWSZ;
        v00 = base[y0 * FW + x0];
        v01 = base[y0 * FW + x1i];
        v10 = base[y1i * FW + x0];
        v11 = base[y1i * FW + x1i];
    }
    float v = hy * hx * v00 + hy * lx * v01 + ly * hx * v10 + ly * lx * v11;
    return valid ? v : 0.f;
}

// ---------------- RoIAlign -> fp32 x (fallback path) ----------------
template<bool TRANS>
__global__ __launch_bounds__(256) void roi_k(const float* __restrict__ feat,
                                             const float* __restrict__ boxes,
                                             float* __restrict__ xout) {
    int pp = blockIdx.x, r = blockIdx.y, c = threadIdx.x;
    int b = r >> 9;
    const float* bx = boxes + (size_t)r * 4;
    float x1 = bx[0] * 0.25f, y1 = bx[1] * 0.25f, x2 = bx[2] * 0.25f, y2 = bx[3] * 0.25f;
    float rw = fmaxf(x2 - x1, 1.0f), rh = fmaxf(y2 - y1, 1.0f);
    float bw = rw / 7.0f, bh = rh / 7.0f;
    int py = pp / 7, px = pp % 7;
    float acc = 0.f;
#pragma unroll
    for (int sy = 0; sy < 2; ++sy)
#pragma unroll
        for (int sx = 0; sx < 2; ++sx)
            acc += bil_sample<TRANS>(feat, b, c,
                                     y1 + ((float)py + 0.25f + 0.5f * (float)sy) * bh,
                                     x1 + ((float)px + 0.25f + 0.5f * (float)sx) * bw);
    xout[(size_t)r * INDIM + pp * 256 + c] = acc * 0.25f;
}

// ---------------- RoIAlign -> split bf16 planes, float4-vectorized ----------------
__global__ __launch_bounds__(256) void roi_split4_k(const float* __restrict__ feat,
                                                    const float* __restrict__ boxes,
                                                    unsigned short* __restrict__ Ap) {
    int tid = threadIdx.x;
    int g = tid >> 7;              // roi within block
    int binhalf = (tid >> 6) & 1;  // bin parity
    int cl = tid & 63;             // channels 4cl..4cl+3
    int r = blockIdx.x * 2 + g;
    int b = r >> 9;
    const float* bx = boxes + (size_t)r * 4;
    float x1 = bx[0] * 0.25f, y1 = bx[1] * 0.25f, x2 = bx[2] * 0.25f, y2 = bx[3] * 0.25f;
    float rw = fmaxf(x2 - x1, 1.0f), rh = fmaxf(y2 - y1, 1.0f);
    float bw = rw / 7.0f, bh = rh / 7.0f;
    int mt = r >> 7, rr = r & 127;
    size_t pstr = (size_t)8 * KKT1 * 4096;
    const float* base = feat + (size_t)b * HWSZ * CFEAT;
    for (int pp = binhalf; pp < 49; pp += 2) {
        int py = pp / 7, px = pp % 7;
        float ax = 0.f, ay = 0.f, az = 0.f, aw = 0.f;
#pragma unroll
        for (int sy = 0; sy < 2; ++sy) {
#pragma unroll
            for (int sx = 0; sx < 2; ++sx) {
                float yy = y1 + ((float)py + 0.25f + 0.5f * (float)sy) * bh;
                float xx = x1 + ((float)px + 0.25f + 0.5f * (float)sx) * bw;
                bool valid = (yy > -1.f) && (yy < (float)FH) && (xx > -1.f) && (xx < (float)FW);
                float yc = fminf(fmaxf(yy, 0.f), (float)(FH - 1));
                float xc = fminf(fmaxf(xx, 0.f), (float)(FW - 1));
                int y0 = (int)floorf(yc), x0 = (int)floorf(xc);
                int y1i = min(y0 + 1, FH - 1), x1i = min(x0 + 1, FW - 1);
                float ly = yc - (float)y0, lx = xc - (float)x0;
                float hy = 1.f - ly, hx = 1.f - lx;
                float w00 = hy * hx, w01 = hy * lx, w10 = ly * hx, w11 = ly * lx;
                if (!valid) { w00 = w01 = w10 = w11 = 0.f; }
                float4 v00 = ((const float4*)(base + (size_t)(y0 * FW + x0) * CFEAT))[cl];
                float4 v01 = ((const float4*)(base + (size_t)(y0 * FW + x1i) * CFEAT))[cl];
                float4 v10 = ((const float4*)(base + (size_t)(y1i * FW + x0) * CFEAT))[cl];
                float4 v11 = ((const float4*)(base + (size_t)(y1i * FW + x1i) * CFEAT))[cl];
                ax += w00 * v00.x + w01 * v01.x + w10 * v10.x + w11 * v11.x;
                ay += w00 * v00.y + w01 * v01.y + w10 * v10.y + w11 * v11.y;
                az += w00 * v00.z + w01 * v01.z + w10 * v10.z + w11 * v11.z;
                aw += w00 * v00.w + w01 * v01.w + w10 * v10.w + w11 * v11.w;
            }
        }
        ax *= 0.25f; ay *= 0.25f; az *= 0.25f; aw *= 0.25f;
        ushort4 h4, m4, l4;
        split3(ax, h4.x, m4.x, l4.x);
        split3(ay, h4.y, m4.y, l4.y);
        split3(az, h4.z, m4.z, l4.z);
        split3(aw, h4.w, m4.w, l4.w);
        int k0 = pp * 256 + cl * 4;
        int kk = k0 >> 5;
        size_t tile = ((size_t)mt * KKT1 + kk) * 4096 + rr * 32 + (k0 & 31);
        *(ushort4*)&Ap[tile] = h4;
        *(ushort4*)&Ap[tile + pstr] = m4;
        *(ushort4*)&Ap[tile + 2 * pstr] = l4;
    }
}

// ---------------- weight split + transpose into tiled planes ----------------
template<bool PERM>
__global__ __launch_bounds__(256) void wsplit_k(const float* __restrict__ W,
                                                unsigned short* __restrict__ out, int kkT) {
    __shared__ float tf[32][132];
    int nt = blockIdx.x, kk = blockIdx.y;
    int t = threadIdx.x;
    int kloc = t >> 3;
    int f4 = t & 7;
    int krow;
    if (PERM) krow = ((kk & 7) * 32 + kloc) * 49 + (kk >> 3);
    else krow = kk * 32 + kloc;
    const float* src = W + (size_t)krow * 1024 + nt * 128;
#pragma unroll
    for (int q = 0; q < 4; ++q) {
        float4 v = *(const float4*)(src + (f4 + q * 8) * 4);
        *(float4*)&tf[kloc][(f4 + q * 8) * 4] = v;
    }
    __syncthreads();
    int r = t >> 1;
    size_t tileBase = ((size_t)nt * kkT + kk) * 4096;
    size_t pstr = (size_t)8 * kkT * 4096;
#pragma unroll
    for (int cc = 0; cc < 2; ++cc) {
        int c = (t & 1) * 2 + cc;
        ushort8v hv, mv, lv;
#pragma unroll
        for (int e = 0; e < 8; ++e) {
            unsigned short h, m, l;
            split3(tf[c * 8 + e][r], h, m, l);
            hv[e] = h; mv[e] = m; lv[e] = l;
        }
        size_t o = tileBase + r * 32 + c * 8;
        *(ushort8v*)&out[o] = hv;
        *(ushort8v*)&out[o + pstr] = mv;
        *(ushort8v*)&out[o + 2 * pstr] = lv;
    }
}

// ---------------- head weights (Wc|Wr, zero-padded to 128 cols) -> planes ----------------
__global__ __launch_bounds__(256) void wsplit_head_k(const float* __restrict__ Wc,
                                                     const float* __restrict__ Wr,
                                                     unsigned short* __restrict__ out) {
    int kk = blockIdx.x, t = threadIdx.x;
    int r = t >> 1;
    int k0 = (t & 1) * 16;
    size_t pstr = (size_t)KKT2 * 4096;
    for (int e = 0; e < 16; ++e) {
        int k = k0 + e;
        int krow = kk * 32 + k;
        float v = 0.f;
        if (r < 81) v = Wc[(size_t)krow * 81 + r];
        else if (r < 85) v = Wr[(size_t)krow * 4 + (r - 81)];
        unsigned short h, m, l;
        split3(v, h, m, l);
        size_t o = (size_t)kk * 4096 + r * 32 + k;
        out[o] = h;
        out[o + pstr] = m;
        out[o + 2 * pstr] = l;
    }
}

// ---------------- MFMA GEMM: single-buffered A, double-buffered B (72 KB) ----------------
// r8 config (best measured): 2 blocks/CU; per kk stage A + prefetch next B,
// s_waitcnt vmcnt(6) keeps B-prefetch in flight across both barriers (T4).
#define TERM16(AF) { _Pragma("unroll") for (int i = 0; i < 4; ++i) _Pragma("unroll") \
    for (int j = 0; j < 4; ++j) acc[i][j] = __builtin_amdgcn_mfma_f32_16x16x32_bf16(AF[i], bf[j], acc[i][j], 0, 0, 0); }

__global__ __launch_bounds__(256) void gemm_mfma_k(const unsigned short* __restrict__ Ap,
                                                   const unsigned short* __restrict__ Bp,
                                                   float* __restrict__ partial,
                                                   int kkT, int kkPer, int NT, int N) {
    __shared__ unsigned short sA[3][4096];        // 24 KB
    __shared__ unsigned short sB[2][3][4096];     // 48 KB
    int tid = threadIdx.x;
    int phys = blockIdx.x;
    int logical = (phys & 7) * (gridDim.x >> 3) + (phys >> 3);
    int tpc = 8 * NT;
    int xy = logical % tpc;
    int ck = logical / tpc;
    int mt = xy & 7, nt = xy >> 3;
    int kk0 = ck * kkPer;
    size_t pstrA = (size_t)8 * kkT * 4096 * 2;    // bytes
    size_t pstrB = (size_t)NT * kkT * 4096 * 2;   // bytes
    const char* aBase = (const char*)(Ap + (size_t)mt * kkT * 4096);
    const char* bBase = (const char*)(Bp + (size_t)nt * kkT * 4096);

    float4v acc[4][4];
#pragma unroll
    for (int i = 0; i < 4; ++i)
#pragma unroll
        for (int j = 0; j < 4; ++j) acc[i][j] = (float4v){0.f, 0.f, 0.f, 0.f};

    int lane = tid & 63, wv = tid >> 6;
    int wr = wv >> 1, wc = wv & 1;
    int ln = lane & 15;
    int q = lane >> 4;
    int qs = (q ^ (ln ^ (ln >> 2))) & 3;
    int aoffE = (wr * 64 + ln) * 32 + qs * 8;
    int boffE = (wc * 64 + ln) * 32 + qs * 8;

    int o0 = tid * 16;
    int o1 = o0 + 4096;
    int s0 = swz8k(o0);
    int s1 = swz8k(o1);

    auto stageA = [&](int kk) {
        const char* at = aBase + (size_t)kk * 8192;
#pragma unroll
        for (int p = 0; p < 3; ++p) {
            gload_lds16(at + (size_t)p * pstrA + s0, (char*)sA[p] + o0);
            gload_lds16(at + (size_t)p * pstrA + s1, (char*)sA[p] + o1);
        }
    };
    auto stageB = [&](int buf, int kk) {
        const char* bt = bBase + (size_t)kk * 8192;
#pragma unroll
        for (int p = 0; p < 3; ++p) {
            gload_lds16(bt + (size_t)p * pstrB + s0, (char*)sB[buf][p] + o0);
            gload_lds16(bt + (size_t)p * pstrB + s1, (char*)sB[buf][p] + o1);
        }
    };

    stageB(0, kk0);   // prologue: prefetch first B tile
    for (int it = 0; it < kkPer; ++it) {
        int cur = it & 1;
        stageA(kk0 + it);
        if (it + 1 < kkPer) {
            stageB(cur ^ 1, kk0 + it + 1);
            asm volatile("s_waitcnt vmcnt(6)" ::: "memory");
        } else {
            asm volatile("s_waitcnt vmcnt(0)" ::: "memory");
        }
        __builtin_amdgcn_s_barrier();
        __builtin_amdgcn_sched_barrier(0);
        short8v af[3][4];
#pragma unroll
        for (int p = 0; p < 3; ++p)
#pragma unroll
            for (int f = 0; f < 4; ++f)
                af[p][f] = *(const short8v*)&sA[p][aoffE + f * 512];
        short8v bf[4];
#pragma unroll
        for (int f = 0; f < 4; ++f) bf[f] = *(const short8v*)&sB[cur][0][boffE + f * 512];
        TERM16(af[0]); TERM16(af[1]); TERM16(af[2]);
#pragma unroll
        for (int f = 0; f < 4; ++f) bf[f] = *(const short8v*)&sB[cur][1][boffE + f * 512];
        TERM16(af[0]); TERM16(af[1]);
#pragma unroll
        for (int f = 0; f < 4; ++f) bf[f] = *(const short8v*)&sB[cur][2][boffE + f * 512];
        TERM16(af[0]);
        __builtin_amdgcn_sched_barrier(0);
        __builtin_amdgcn_s_barrier();
    }
    float* outp = partial + (size_t)ck * 1024 * N;
    int row0 = mt * 128 + wr * 64 + (lane >> 4) * 4;
    int col = nt * 128 + wc * 64 + ln;
#pragma unroll
    for (int i = 0; i < 4; ++i)
#pragma unroll
        for (int j = 0; j < 4; ++j)
#pragma unroll
            for (int qq = 0; qq < 4; ++qq)
                outp[(size_t)(row0 + i * 16 + qq) * N + col + j * 16] = acc[i][j][qq];
}

// ---------------- split-K reduce + bias + relu -> split planes (KKT2 layout) ----------------
template<int NS>
__global__ void reduce8_k(const float* __restrict__ partial, const float* __restrict__ bias,
                          unsigned short* __restrict__ planes) {
    int i = blockIdx.x * 256 + threadIdx.x;
    float s = 0.f;
#pragma unroll
    for (int c = 0; c < NS; ++c) s += partial[((size_t)c << 20) + i];
    s += bias[i & 1023];
    s = fmaxf(s, 0.f);
    int m = i >> 10, n = i & 1023;
    int mt = m >> 7, rr = m & 127, kk = n >> 5;
    unsigned short h, mm_, l;
    split3(s, h, mm_, l);
    size_t tile = ((size_t)mt * KKT2 + kk) * 4096 + rr * 32 + (n & 31);
    size_t pstr = (size_t)8 * KKT2 * 4096;
    planes[tile] = h;
    planes[tile + pstr] = mm_;
    planes[tile + 2 * pstr] = l;
}

// ---------------- fused head finalize + box decode (one block per roi) ----------------
__global__ __launch_bounds__(128) void head_dec_k(const float* __restrict__ partial,
                                                  const float* __restrict__ bc,
                                                  const float* __restrict__ br,
                                                  const float* __restrict__ prev,
                                                  float* __restrict__ logits,
                                                  float* __restrict__ nxt,
                                                  float wx, float wy, float ww, float wh,
                                                  int write_logits) {
    int m = blockIdx.x;
    int tid = threadIdx.x;
    __shared__ float dl[4];
    if (tid < 85) {
        float s = 0.f;
#pragma unroll
        for (int c = 0; c < 8; ++c) s += partial[(size_t)c * 131072 + m * 128 + tid];
        if (tid < 81) {
            if (write_logits) logits[(size_t)m * NCLS + tid] = s + bc[tid];
        } else {
            dl[tid - 81] = s + br[tid - 81];
        }
    }
    __syncthreads();
    if (tid == 0) {
        const float* p = prev + (size_t)m * 4;
        float px1 = p[0], py1 = p[1], px2 = p[2], py2 = p[3];
        float pw = fmaxf(px2 - px1, 1e-6f), ph = fmaxf(py2 - py1, 1e-6f);
        float pcx = px1 + 0.5f * pw, pcy = py1 + 0.5f * ph;
        float dx = dl[0] * wx, dy = dl[1] * wy;
        float dw = fminf(dl[2] * ww, CLIPV);
        float dh = fminf(dl[3] * wh, CLIPV);
        float gx = dx * pw + pcx, gy = dy * ph + pcy;
        float gw = expf(dw) * pw, gh = expf(dh) * ph;
        nxt[(size_t)m * 4 + 0] = fminf(fmaxf(gx - 0.5f * gw, 0.f), 800.f);
        nxt[(size_t)m * 4 + 1] = fminf(fmaxf(gy - 0.5f * gh, 0.f), 800.f);
        nxt[(size_t)m * 4 + 2] = fminf(fmaxf(gx + 0.5f * gw, 0.f), 800.f);
        nxt[(size_t)m * 4 + 3] = fminf(fmaxf(gy + 0.5f * gh, 0.f), 800.f);
    }
}

// ---------------- old fp32 GEMM (fallback) ----------------
template<bool PERM>
__global__ __launch_bounds__(256) void gemm_k(const float* __restrict__ A,
                                              const float* __restrict__ Bm,
                                              float* __restrict__ partial,
                                              int K_total, int Kchunk) {
    const int M = 1024, N = 1024;
    __shared__ float As[2][16][128];
    __shared__ float Bs[2][16][64];
    int tid = threadIdx.x;
    int mb = blockIdx.x & 7;
    int nb = blockIdx.x >> 3;
    int ck = blockIdx.y;
    int k0 = ck * Kchunk;
    int am = tid >> 1;
    int ak = (tid & 1) * 8;
    int bk = tid >> 4;
    int bn = (tid & 15) * 4;
    int ty = tid >> 4, tx = tid & 15;
    const float* Aptr = A + (size_t)(mb * 128 + am) * K_total + k0 + ak;

    float acc[8][4];
#pragma unroll
    for (int i = 0; i < 8; ++i)
#pragma unroll
        for (int j = 0; j < 4; ++j) acc[i][j] = 0.f;

    auto bRowPtr = [&](int kk) -> const float* {
        int row = PERM ? ((kk & 255) * 49 + (kk >> 8)) : kk;
        return Bm + (size_t)row * N + nb * 64 + bn;
    };

    int T = Kchunk / 16;
    float4 a0 = *(const float4*)(Aptr);
    float4 a1 = *(const float4*)(Aptr + 4);
    float4 b0 = *(const float4*)bRowPtr(k0 + bk);
    As[0][ak + 0][am] = a0.x; As[0][ak + 1][am] = a0.y; As[0][ak + 2][am] = a0.z; As[0][ak + 3][am] = a0.w;
    As[0][ak + 4][am] = a1.x; As[0][ak + 5][am] = a1.y; As[0][ak + 6][am] = a1.z; As[0][ak + 7][am] = a1.w;
    *(float4*)&Bs[0][bk][bn] = b0;
    __syncthreads();

    int p = 0;
    for (int t = 0; t < T; ++t) {
        if (t + 1 < T) {
            a0 = *(const float4*)(Aptr + (t + 1) * 16);
            a1 = *(const float4*)(Aptr + (t + 1) * 16 + 4);
            b0 = *(const float4*)bRowPtr(k0 + (t + 1) * 16 + bk);
        }
#pragma unroll
        for (int k = 0; k < 16; ++k) {
            float4 av0 = *(const float4*)&As[p][k][ty * 8];
            float4 av1 = *(const float4*)&As[p][k][ty * 8 + 4];
            float4 bv = *(const float4*)&Bs[p][k][tx * 4];
            float ar[8] = {av0.x, av0.y, av0.z, av0.w, av1.x, av1.y, av1.z, av1.w};
            float br_[4] = {bv.x, bv.y, bv.z, bv.w};
#pragma unroll
            for (int i = 0; i < 8; ++i)
#pragma unroll
                for (int j = 0; j < 4; ++j) acc[i][j] = fmaf(ar[i], br_[j], acc[i][j]);
        }
        if (t + 1 < T) {
            __syncthreads();
            int qb = 1 - p;
            As[qb][ak + 0][am] = a0.x; As[qb][ak + 1][am] = a0.y; As[qb][ak + 2][am] = a0.z; As[qb][ak + 3][am] = a0.w;
            As[qb][ak + 4][am] = a1.x; As[qb][ak + 5][am] = a1.y; As[qb][ak + 6][am] = a1.z; As[qb][ak + 7][am] = a1.w;
            *(float4*)&Bs[qb][bk][bn] = b0;
            __syncthreads();
            p = qb;
        }
    }
    float* out = partial + ((size_t)ck * M + mb * 128 + ty * 8) * N + nb * 64 + tx * 4;
#pragma unroll
    for (int i = 0; i < 8; ++i) {
        float4 v = make_float4(acc[i][0], acc[i][1], acc[i][2], acc[i][3]);
        *(float4*)(out + (size_t)i * N) = v;
    }
}

__global__ void reduce4_k(const float* __restrict__ partial, const float* __restrict__ bias,
                          float* __restrict__ out) {
    const int MN = 1024 * 1024;
    int i = blockIdx.x * 256 + threadIdx.x;
    if (i >= MN) return;
    float s = partial[i] + partial[(size_t)MN + i] + partial[(size_t)2 * MN + i] + partial[(size_t)3 * MN + i];
    s += bias[i & 1023];
    out[i] = fmaxf(s, 0.f);
}

// ---------------- cls + reg heads (fallback) ----------------
__global__ __launch_bounds__(128) void head_k(const float* __restrict__ h,
                                              const float* __restrict__ Wc, const float* __restrict__ bc,
                                              const float* __restrict__ Wr, const float* __restrict__ br,
                                              float* __restrict__ logits, float* __restrict__ deltas,
                                              int write_logits) {
    __shared__ float hs[1024];
    int m = blockIdx.x;
    int tid = threadIdx.x;
    const float4* hp = (const float4*)(h + (size_t)m * 1024);
    ((float4*)hs)[tid] = hp[tid];
    ((float4*)hs)[tid + 128] = hp[tid + 128];
    __syncthreads();
    int j = tid;
    if (j < 85) {
        bool is_cls = j < 81;
        const float* Wp = is_cls ? Wc : Wr;
        int stride = is_cls ? 81 : 4;
        int col = is_cls ? j : j - 81;
        float s0 = 0.f, s1 = 0.f, s2 = 0.f, s3 = 0.f;
        for (int k = 0; k < 1024; k += 4) {
            s0 = fmaf(hs[k + 0], Wp[(k + 0) * stride + col], s0);
            s1 = fmaf(hs[k + 1], Wp[(k + 1) * stride + col], s1);
            s2 = fmaf(hs[k + 2], Wp[(k + 2) * stride + col], s2);
            s3 = fmaf(hs[k + 3], Wp[(k + 3) * stride + col], s3);
        }
        float s = (s0 + s1) + (s2 + s3);
        if (is_cls) {
            if (write_logits) logits[(size_t)m * NCLS + col] = s + bc[col];
        } else {
            deltas[(size_t)m * 4 + col] = s + br[col];
        }
    }
}

// ---------------- box decode (fallback) ----------------
__global__ void decode_k(const float* __restrict__ prev, const float* __restrict__ deltas,
                         float* __restrict__ nxt, float wx, float wy, float ww, float wh) {
    int r = blockIdx.x * 256 + threadIdx.x;
    if (r >= NROI) return;
    const float* p = prev + (size_t)r * 4;
    const float* d = deltas + (size_t)r * 4;
    float px1 = p[0], py1 = p[1], px2 = p[2], py2 = p[3];
    float pw = fmaxf(px2 - px1, 1e-6f), ph = fmaxf(py2 - py1, 1e-6f);
    float pcx = px1 + 0.5f * pw, pcy = py1 + 0.5f * ph;
    float dx = d[0] * wx, dy = d[1] * wy;
    float dw = fminf(d[2] * ww, CLIPV);
    float dh = fminf(d[3] * wh, CLIPV);
    float gx = dx * pw + pcx, gy = dy * ph + pcy;
    float gw = expf(dw) * pw, gh = expf(dh) * ph;
    nxt[(size_t)r * 4 + 0] = fminf(fmaxf(gx - 0.5f * gw, 0.f), 800.f);
    nxt[(size_t)r * 4 + 1] = fminf(fmaxf(gy - 0.5f * gh, 0.f), 800.f);
    nxt[(size_t)r * 4 + 2] = fminf(fmaxf(gx + 0.5f * gw, 0.f), 800.f);
    nxt[(size_t)r * 4 + 3] = fminf(fmaxf(gy + 0.5f * gh, 0.f), 800.f);
}

// ---------------- fused softmax + score build (one block per roi row) ----------------
__global__ __launch_bounds__(128) void softmax_build_k(const float* __restrict__ logits,
                                                       const float* __restrict__ boxes,
                                                       float* __restrict__ sc,
                                                       int* __restrict__ vcount) {
    __shared__ float red[128];
    int m = blockIdx.x;           // 0..1023
    int b = m >> 9, rr = m & 511;
    int tid = threadIdx.x;
    float v = (tid < NCLS) ? logits[(size_t)m * NCLS + tid] : -FLT_MAX;
    red[tid] = v;
    __syncthreads();
    for (int o = 64; o; o >>= 1) {
        if (tid < o) red[tid] = fmaxf(red[tid], red[tid + o]);
        __syncthreads();
    }
    float mx = red[0];
    __syncthreads();
    float e = (tid < NCLS) ? expf(v - mx) : 0.f;
    red[tid] = e;
    __syncthreads();
    for (int o = 64; o; o >>= 1) {
        if (tid < o) red[tid] += red[tid + o];
        __syncthreads();
    }
    float ssum = red[0];
    const float* bx = boxes + (size_t)m * 4;
    bool ok = (bx[2] - bx[0] >= 1.f) && (bx[3] - bx[1] >= 1.f);
    if (tid >= 1 && tid < NCLS) {
        float p = e / ssum;
        float sval = (p > 0.05f && ok) ? p : -1.0f;
        sc[(size_t)b * NCAND + rr * 80 + (tid - 1)] = sval;
        if (sval > 0.f) atomicAdd(&vcount[b], 1);
    }
}

// ---------------- pivot search, register-cached (only matters when >4096 valid) ----------------
__global__ __launch_bounds__(1024) void find_pivot_k(const float* __restrict__ sc,
                                                     const int* __restrict__ vcount,
                                                     float* __restrict__ pivot) {
    int b = blockIdx.x;
    const float* s = sc + (size_t)b * NCAND;
    __shared__ int tot;
    int V = vcount[b];
    if (V <= CAP) {
        if (threadIdx.x == 0) pivot[b] = 0.f;
        return;
    }
    // cache all 40 scores/thread in registers: the 31 bit-search passes become
    // pure VALU instead of 31x 160KB L2 re-reads from a single CU.
    float v[40];
#pragma unroll
    for (int i = 0; i < 40; ++i) v[i] = s[threadIdx.x + i * 1024];
    unsigned u = 0;
    for (int bit = 30; bit >= 0; --bit) {
        unsigned cand = u | (1u << bit);
        float cf = __uint_as_float(cand);
        if (threadIdx.x == 0) tot = 0;
        __syncthreads();
        int cnt = 0;
#pragma unroll
        for (int i = 0; i < 40; ++i) cnt += (v[i] >= cf) ? 1 : 0;
        for (int o = 32; o; o >>= 1) cnt += __shfl_down(cnt, o);
        if ((threadIdx.x & 63) == 0) atomicAdd(&tot, cnt);
        __syncthreads();
        if (tot >= NSEL) u = cand;
        __syncthreads();
    }
    if (threadIdx.x == 0) pivot[b] = __uint_as_float(u);
}

// ---------------- compact candidates ----------------
__global__ void compact_k(const float* __restrict__ sc, const float* __restrict__ pivot,
                          float* __restrict__ ckey, int* __restrict__ cidx, int* __restrict__ ccount) {
    int f = blockIdx.x * 256 + threadIdx.x;
    if (f >= NB * NCAND) return;
    int b = f / NCAND, ff = f % NCAND;
    float s = sc[f];
    float pv = pivot[b];
    if (s > 0.f && s >= pv) {
        int slot = atomicAdd(&ccount[b], 1);
        if (slot < CAP) {
            ckey[(size_t)b * CAP + slot] = s;
            cidx[(size_t)b * CAP + slot] = ff;
        }
    }
}

// ---------------- bitonic sort + selection ----------------
__global__ __launch_bounds__(1024) void sort_select_k(const float* __restrict__ ckey,
                                                      const int* __restrict__ cidx,
                                                      const int* __restrict__ ccount,
                                                      const float* __restrict__ boxes,
                                                      float* __restrict__ selb, float* __restrict__ seloff,
                                                      float* __restrict__ selsc, int* __restrict__ sellab,
                                                      unsigned long long* __restrict__ vmask) {
    int b = blockIdx.x;
    __shared__ float ks[CAP];
    __shared__ int is[CAP];
    __shared__ float rmax[1024];
    int cnt = min(ccount[b], CAP);
    for (int i = threadIdx.x; i < CAP; i += 1024) {
        if (i < cnt) {
            ks[i] = ckey[(size_t)b * CAP + i];
            is[i] = cidx[(size_t)b * CAP + i];
        } else {
            ks[i] = -FLT_MAX;
            is[i] = 0x7FFFFFFF;
        }
    }
    __syncthreads();
    for (int k = 2; k <= CAP; k <<= 1) {
        for (int j = k >> 1; j > 0; j >>= 1) {
            for (int t = threadIdx.x; t < CAP; t += 1024) {
                int l = t ^ j;
                if (l > t) {
                    bool up = ((t & k) == 0);
                    float a = ks[t], bb = ks[l];
                    int ia = is[t], ib = is[l];
                    bool a_first = (a > bb) || (a == bb && ia < ib);
                    bool doswap = up ? !a_first : a_first;
                    if (doswap) {
                        ks[t] = bb; ks[l] = a;
                        is[t] = ib; is[l] = ia;
                    }
                }
            }
            __syncthreads();
        }
    }
    float lm = -FLT_MAX;
    for (int i = threadIdx.x; i < NSEL; i += 1024) {
        if (ks[i] > 0.f) {
            const float* bb = boxes + (size_t)(b * NPROP + is[i] / 80) * 4;
            lm = fmaxf(lm, fmaxf(fmaxf(bb[0], bb[1]), fmaxf(bb[2], bb[3])));
        }
    }
    rmax[threadIdx.x] = lm;
    __syncthreads();
    for (int o = 512; o; o >>= 1) {
        if (threadIdx.x < o) rmax[threadIdx.x] = fmaxf(rmax[threadIdx.x], rmax[threadIdx.x + o]);
        __syncthreads();
    }
    float maxb = (rmax[0] > -FLT_MAX) ? rmax[0] : 0.f;
    __syncthreads();
    for (int pass = 0; pass < 2; ++pass) {
        int i = pass * 1024 + threadIdx.x;
        bool v = ks[i] > 0.f;
        int idx = is[i];
        int rr = idx / 80;
        int cls = idx % 80 + 1;
        float b0 = 0.f, b1 = 0.f, b2 = 0.f, b3 = 0.f, offv = 0.f;
        if (v) {
            const float* bb = boxes + (size_t)(b * NPROP + rr) * 4;
            b0 = bb[0]; b1 = bb[1]; b2 = bb[2]; b3 = bb[3];
            offv = (maxb + 1.f) * (float)cls;
        }
        float* sb = selb + ((size_t)b * NSEL + i) * 4;
        sb[0] = b0; sb[1] = b1; sb[2] = b2; sb[3] = b3;
        float* so = seloff + ((size_t)b * NSEL + i) * 4;
        so[0] = b0 + offv; so[1] = b1 + offv; so[2] = b2 + offv; so[3] = b3 + offv;
        selsc[(size_t)b * NSEL + i] = v ? ks[i] : 0.f;
        sellab[(size_t)b * NSEL + i] = cls;
        unsigned long long m = __ballot(v);
        if ((threadIdx.x & 63) == 0) vmask[b * 32 + pass * 16 + (threadIdx.x >> 6)] = m;
    }
}

// ---------------- suppression bitmask (upper triangle only) ----------------
__global__ __launch_bounds__(256) void sup_k(const float* __restrict__ seloff,
                                             const float* __restrict__ selsc,
                                             unsigned long long* __restrict__ sup) {
    int b = blockIdx.y;
    int wave = threadIdx.x >> 6;
    int lane = threadIdx.x & 63;
    int pair = blockIdx.x * 4 + wave;
    int i = pair >> 5;
    int w = pair & 31;
    int j = w * 64 + lane;
    unsigned long long m = 0;
    if (w >= (i >> 6) && selsc[(size_t)b * NSEL + i] > 0.f) {
        const float* oi = seloff + ((size_t)b * NSEL + i) * 4;
        const float* oj = seloff + ((size_t)b * NSEL + j) * 4;
        float ax1 = oi[0], ay1 = oi[1], ax2 = oi[2], ay2 = oi[3];
        float bx1 = oj[0], by1 = oj[1], bx2 = oj[2], by2 = oj[3];
        float areaA = (ax2 - ax1) * (ay2 - ay1);
        float areaB = (bx2 - bx1) * (by2 - by1);
        float ltx = fmaxf(ax1, bx1), lty = fmaxf(ay1, by1);
        float rbx = fminf(ax2, bx2), rby = fminf(ay2, by2);
        float iw = fmaxf(rbx - ltx, 0.f), ih = fmaxf(rby - lty, 0.f);
        float inter = iw * ih;
        float iou = inter / (areaA + areaB - inter + 1e-12f);
        m = __ballot(iou > 0.5f);
    }
    if (lane == 0) sup[((size_t)b * NSEL + i) * 32 + w] = m;
}

// ---------------- NMS scan: word-blocked, scalar serial chain, early exit ----------------
__global__ __launch_bounds__(256) void nms_scan_k(const unsigned long long* __restrict__ vmask,
                                                  const unsigned long long* __restrict__ sup,
                                                  const float* __restrict__ selb,
                                                  const float* __restrict__ selsc,
                                                  const int* __restrict__ sellab,
                                                  float* __restrict__ out) {
    int b = blockIdx.x;
    __shared__ unsigned long long keepw[32];
    __shared__ int pref[33];
    int tid = threadIdx.x;
    if (tid < 64) {
        int lane = tid;
        unsigned long long kw = (lane < 32) ? vmask[b * 32 + lane] : 0ull;
        const unsigned long long* supB = sup + (size_t)b * NSEL * 32;
        int kept = 0;
        for (int w = 0; w < 32; ++w) {
            unsigned long long cur = __shfl(kw, w);
            if (cur) {
                unsigned long long R = supB[(size_t)(w * 64 + lane) * 32 + w];
                for (int b0 = 0; b0 < 64; b0 += 8) {
                    unsigned long long r0 = __shfl(R, b0 + 0);
                    unsigned long long r1 = __shfl(R, b0 + 1);
                    unsigned long long r2 = __shfl(R, b0 + 2);
                    unsigned long long r3 = __shfl(R, b0 + 3);
                    unsigned long long r4 = __shfl(R, b0 + 4);
                    unsigned long long r5 = __shfl(R, b0 + 5);
                    unsigned long long r6 = __shfl(R, b0 + 6);
                    unsigned long long r7 = __shfl(R, b0 + 7);
                    unsigned long long hi;
#define NMS_STEP(rr_, dd_) { int bb = b0 + dd_; \
                    hi = (bb == 63) ? 0ull : (~0ull << (bb + 1)); \
                    cur &= ~((0ull - ((cur >> bb) & 1ull)) & rr_ & hi); }
                    NMS_STEP(r0, 0) NMS_STEP(r1, 1) NMS_STEP(r2, 2) NMS_STEP(r3, 3)
                    NMS_STEP(r4, 4) NMS_STEP(r5, 5) NMS_STEP(r6, 6) NMS_STEP(r7, 7)
#undef NMS_STEP
                }
                kept += __popcll(cur);
                if (lane == w) kw = cur;
                if (kept >= DETS) break;
                int v = lane & 31;
                int h = lane >> 5;
                unsigned long long acc = 0;
                const unsigned long long* rowb = supB + (size_t)(w * 64 + h) * 32 + v;
#pragma unroll 8
                for (int t = 0; t < 32; ++t) {
                    unsigned long long msk = 0ull - ((cur >> (h + 2 * t)) & 1ull);
                    acc |= rowb[(size_t)(2 * t) * 32] & msk;
                }
                acc |= __shfl_xor(acc, 32);
                if (lane < 32 && lane > w) kw &= ~acc;
            }
        }
        if (lane < 32) keepw[lane] = kw;
    }
    __syncthreads();
    if (tid == 0) {
        int s = 0;
        for (int w = 0; w < 32; ++w) { pref[w] = s; s += __popcll(keepw[w]); }
        pref[32] = s;
    }
    __syncthreads();
    for (int i = tid; i < 600; i += 256) {
        if (i < 400) out[b * 400 + i] = 0.f;
        else if (i < 500) out[800 + b * 100 + (i - 400)] = 0.f;
        else out[1000 + b * 100 + (i - 500)] = 0.f;
    }
    __syncthreads();
    for (int e = tid; e < NSEL; e += 256) {
        int w = e >> 6;
        unsigned long long kw = keepw[w];
        if ((kw >> (e & 63)) & 1ull) {
            int rank = pref[w] + __popcll(kw & ((1ull << (e & 63)) - 1ull));
            if (rank < DETS) {
                const float* sb = selb + ((size_t)b * NSEL + e) * 4;
                out[b * 400 + rank * 4 + 0] = sb[0];
                out[b * 400 + rank * 4 + 1] = sb[1];
                out[b * 400 + rank * 4 + 2] = sb[2];
                out[b * 400 + rank * 4 + 3] = sb[3];
                out[800 + b * 100 + rank] = selsc[(size_t)b * NSEL + e];
                out[1000 + b * 100 + rank] = (float)sellab[(size_t)b * NSEL + e];
            }
        }
    }
}

extern "C" void kernel_launch(void* const* d_in, const int* in_sizes, int n_in,
                              void* d_out, int out_size, void* d_ws, size_t ws_size,
                              hipStream_t stream) {
    const float* features = (const float*)d_in[0];
    const float* proposals = (const float*)d_in[1];
    const float* W1 = (const float*)d_in[2];
    const float* b1 = (const float*)d_in[3];
    const float* W2 = (const float*)d_in[4];
    const float* b2 = (const float*)d_in[5];
    const float* Wc = (const float*)d_in[6];
    const float* bc = (const float*)d_in[7];
    const float* Wr = (const float*)d_in[8];
    const float* br = (const float*)d_in[9];

    char* ws = (char*)d_ws;
    size_t off = 0;
    auto alloc = [&](size_t bytes) -> void* {
        void* p = ws + off;
        off += (bytes + 255) & ~(size_t)255;
        return p;
    };

    float* logits = (float*)alloc((size_t)NROI * NCLS * 4);
    float* deltas = (float*)alloc((size_t)NROI * 4 * 4);
    float* cur1 = (float*)alloc((size_t)NROI * 4 * 4);
    float* cur2 = (float*)alloc((size_t)NROI * 4 * 4);
    float* cur3 = (float*)alloc((size_t)NROI * 4 * 4);
    float* sc = (float*)alloc((size_t)NB * NCAND * 4);
    float* ckey = (float*)alloc((size_t)NB * CAP * 4);
    int* cidx = (int*)alloc((size_t)NB * CAP * 4);
    int* counters = (int*)alloc(256);
    float* pivot = (float*)(counters + 4);
    float* selb = (float*)alloc((size_t)NB * NSEL * 4 * 4);
    float* seloff = (float*)alloc((size_t)NB * NSEL * 4 * 4);
    float* selsc = (float*)alloc((size_t)NB * NSEL * 4);
    int* sellab = (int*)alloc((size_t)NB * NSEL * 4);
    unsigned long long* vmask = (unsigned long long*)alloc((size_t)NB * 32 * 8);
    unsigned long long* sup = (unsigned long long*)alloc((size_t)NB * NSEL * 32 * 8);

    const float stds[3][4] = {{0.1f, 0.1f, 0.2f, 0.2f},
                              {0.05f, 0.05f, 0.1f, 0.1f},
                              {0.033f, 0.033f, 0.067f, 0.067f}};
    float* curbufs[3] = {cur1, cur2, cur3};
    const float* curp = proposals;

    size_t planes1 = (size_t)3 * 8 * KKT1 * 4096 * 2;   // 77 MB
    size_t planes2 = (size_t)3 * 8 * KKT2 * 4096 * 2;   // 6.3 MB
    size_t planesH = (size_t)3 * 1 * KKT2 * 4096 * 2;   // 0.79 MB
    size_t mfma_need = planes1 * 2 + planes2 * 3 + planesH +
                       (size_t)SPLITK * (1 << 20) * 4 +
                       (size_t)NB * HWSZ * CFEAT * 4 + 65536;

    zero_ints_k<<<1, 64, 0, stream>>>(counters, 4);

    if (off + mfma_need <= ws_size) {
        // ================= MFMA split-bf16 path =================
        unsigned short* Ap1 = (unsigned short*)alloc(planes1);
        unsigned short* Bp1 = (unsigned short*)alloc(planes1);
        unsigned short* h1p = (unsigned short*)alloc(planes2);
        unsigned short* W2Tp = (unsigned short*)alloc(planes2);
        unsigned short* h2p = (unsigned short*)alloc(planes2);
        unsigned short* Whp = (unsigned short*)alloc(planesH);
        float* partial = (float*)alloc((size_t)SPLITK * (1 << 20) * 4);
        float* featT = (float*)alloc((size_t)NB * HWSZ * CFEAT * 4);

        transpose_k<<<dim3(1250, 8, 2), dim3(32, 8), 0, stream>>>(features, featT);

        for (int s = 0; s < 3; ++s) {
            roi_split4_k<<<dim3(NROI / 2), 256, 0, stream>>>(featT, curp, Ap1);
            wsplit_k<true><<<dim3(8, KKT1), 256, 0, stream>>>(W1 + (size_t)s * INDIM * FCD, Bp1, KKT1);
            gemm_mfma_k<<<dim3(64 * SPLITK), 256, 0, stream>>>(Ap1, Bp1, partial, KKT1, KKT1 / SPLITK, 8, 1024);
            reduce8_k<SPLITK><<<4096, 256, 0, stream>>>(partial, b1 + s * FCD, h1p);
            wsplit_k<false><<<dim3(8, KKT2), 256, 0, stream>>>(W2 + (size_t)s * FCD * FCD, W2Tp, KKT2);
            gemm_mfma_k<<<dim3(512), 256, 0, stream>>>(h1p, W2Tp, partial, KKT2, 4, 8, 1024);
            reduce8_k<8><<<4096, 256, 0, stream>>>(partial, b2 + s * FCD, h2p);
            wsplit_head_k<<<dim3(KKT2), 256, 0, stream>>>(Wc + (size_t)s * FCD * NCLS,
                                                          Wr + (size_t)s * FCD * 4, Whp);
            gemm_mfma_k<<<dim3(64), 256, 0, stream>>>(h2p, Whp, partial, KKT2, 4, 1, 128);
            head_dec_k<<<dim3(NROI), 128, 0, stream>>>(partial, bc + s * NCLS, br + s * 4,
                                                       curp, logits, curbufs[s],
                                                       stds[s][0], stds[s][1], stds[s][2], stds[s][3],
                                                       (s == 2) ? 1 : 0);
            curp = curbufs[s];
        }
    } else {
        // ================= fp32 fallback path =================
        float* x = (float*)alloc((size_t)NROI * INDIM * 4);
        float* partial = (float*)alloc((size_t)4 * 1024 * 1024 * 4);
        float* h1 = (float*)alloc((size_t)NROI * FCD * 4);
        float* h2 = (float*)alloc((size_t)NROI * FCD * 4);
        float* featT = (float*)alloc((size_t)NB * HWSZ * CFEAT * 4);
        bool use_trans = (off <= ws_size);

        if (use_trans)
            transpose_k<<<dim3(1250, 8, 2), dim3(32, 8), 0, stream>>>(features, featT);

        for (int s = 0; s < 3; ++s) {
            if (use_trans)
                roi_k<true><<<dim3(49, 1024), 256, 0, stream>>>(featT, curp, x);
            else
                roi_k<false><<<dim3(49, 1024), 256, 0, stream>>>(features, curp, x);
            gemm_k<true><<<dim3(128, 4), 256, 0, stream>>>(x, W1 + (size_t)s * INDIM * FCD, partial, INDIM, 3136);
            reduce4_k<<<4096, 256, 0, stream>>>(partial, b1 + s * FCD, h1);
            gemm_k<false><<<dim3(128, 4), 256, 0, stream>>>(h1, W2 + (size_t)s * FCD * FCD, partial, FCD, 256);
            reduce4_k<<<4096, 256, 0, stream>>>(partial, b2 + s * FCD, h2);
            head_k<<<1024, 128, 0, stream>>>(h2, Wc + (size_t)s * FCD * NCLS, bc + s * NCLS,
                                             Wr + (size_t)s * FCD * 4, br + s * 4,
                                             logits, deltas, (s == 2) ? 1 : 0);
            decode_k<<<4, 256, 0, stream>>>(curp, deltas, curbufs[s],
                                            stds[s][0], stds[s][1], stds[s][2], stds[s][3]);
            curp = curbufs[s];
        }
    }

    softmax_build_k<<<dim3(NROI), 128, 0, stream>>>(logits, curp, sc, counters);
    find_pivot_k<<<2, 1024, 0, stream>>>(sc, counters, pivot);
    compact_k<<<320, 256, 0, stream>>>(sc, pivot, ckey, cidx, counters + 2);
    sort_select_k<<<2, 1024, 0, stream>>>(ckey, cidx, counters + 2, curp, selb, seloff, selsc, sellab, vmask);
    sup_k<<<dim3(16384, 2), 256, 0, stream>>>(seloff, selsc, sup);
    nms_scan_k<<<2, 256, 0, stream>>>(vmask, sup, selb, selsc, sellab, (float*)d_out);
}